// Round 13
// baseline (163.869 us; speedup 1.0000x reference)
//
#include <hip/hip_runtime.h>
#include <hip/hip_bf16.h>
#include <math.h>
#include <float.h>

typedef __fp16 f16x8  __attribute__((ext_vector_type(8)));
typedef float  f32x16 __attribute__((ext_vector_type(16)));
typedef float  f32x4  __attribute__((ext_vector_type(4)));
typedef float  f32x2  __attribute__((ext_vector_type(2)));

// Per-band sub-permutation tables (verified conflict-neutral; correctness-proven).
#define DY_TAB 0xA524A509A502A540ULL
#define DX_TAB 0x446A444A44924924ULL

// ============================ Kernel 1: router =============================
// conv1(f32 fma) -> relu -> conv2(MFMA 32x32x16)+relu+maxpool -> fc -> softmax
// LDS arena (22704 B -> 7 blocks/CU by LDS; was 28.5 KB / ~3 resident):
//   spad   f32[32][36]          @0      4608   padded input (row+2, col+4)
//     pooled f32[1296] @0 overlay (spad dead after conv1; barrier-2 separated)
//   sh1T   f16[31][35][8]       @5184   17360  conv1 out, ch-innermost, stride 35
//   swred  f32[40]              @22544  160
// bfrag is built straight from global w2g (12.8 KB, L1-resident) — no LDS
// staging buffer, no staging dependency chain.
__global__ __launch_bounds__(256, 4) void k1_router(
    const float* __restrict__ xg,
    const float* __restrict__ w1g,
    const float* __restrict__ b1g,
    const float* __restrict__ w2g,
    const float* __restrict__ b2g,
    const float* __restrict__ fcwg,
    const float* __restrict__ fcbg,
    float* __restrict__ wsp)
{
    __shared__ __align__(16) char lds[22704];
    float*  spad   = (float*)(lds + 0);
    float*  pooled = (float*)(lds + 0);
    __fp16* sh1T   = (__fp16*)(lds + 5184);
    float*  swred  = (float*)(lds + 22544);

    const int tid  = threadIdx.x;
    const int b    = blockIdx.x;
    const int lane = tid & 63;
    const int wid  = tid >> 6;

    // wave-even conv1/x-load task: 49 tasks per wave (lane<49), tau in [0,196)
    const int ct = wid * 49 + lane;
    const int yy = ct / 7, q = ct - yy * 7;          // row, col-quad

    // ---- phase A: border-zero spad + border-zero sh1T + load x ----
    f32x4 z4 = {0.f, 0.f, 0.f, 0.f};
    // spad border only (rows 0,1,30,31 full; rows 2..29 units 0 and 8)
    for (int i = tid; i < 92; i += 256) {
        int row, cu;
        if (i < 36) { int r = i / 9; cu = i - 9 * r; row = r < 2 ? r : 28 + r; }
        else        { int j = i - 36; row = 2 + (j >> 1); cu = (j & 1) << 3; }
        ((f32x4*)spad)[row * 9 + cu] = z4;
    }
    // sh1T border only: zero rows {0,1,30} all cols + rows 2..29 cols {0,1,30}.
    for (int i = tid; i < 189; i += 256) {
        int row, col;
        if (i < 105) { int r = i / 35; row = (r == 2) ? 30 : r; col = i - 35 * r; }
        else         { int j = i - 105; row = 2 + j / 3; int cm = j - 3 * (j / 3);
                       col = (cm == 2) ? 30 : cm; }
        ((f32x4*)sh1T)[row * 35 + col] = z4;
    }
    if (lane < 49) {
        f32x4 v = *((const f32x4*)(xg + (size_t)b * 784 + yy * 28 + q * 4));
        *((f32x4*)(spad + (yy + 2) * 36 + q * 4 + 4)) = v;
    }
    __syncthreads();   // barrier 1

    // ---- phase B: conv1 f32 (49 tasks/wave) + B-fragment build from GLOBAL ----
    if (lane < 49) {
        float o[8][4];
        #pragma unroll
        for (int c = 0; c < 8; ++c) {
            const float bv = b1g[c];                 // uniform -> SGPR
            #pragma unroll
            for (int px = 0; px < 4; ++px) o[c][px] = bv;
        }
        #pragma unroll
        for (int r = 0; r < 5; ++r) {
            const float* rowp = spad + (yy + r) * 36 + q * 4;
            f32x4 a0 = ((const f32x4*)rowp)[0];
            f32x4 a1 = ((const f32x4*)rowp)[1];
            f32x4 a2 = ((const f32x4*)rowp)[2];
            float u[12] = {a0[0],a0[1],a0[2],a0[3], a1[0],a1[1],a1[2],a1[3],
                           a2[0],a2[1],a2[2],a2[3]};
            #pragma unroll
            for (int c = 0; c < 8; ++c)
                #pragma unroll
                for (int kx = 0; kx < 5; ++kx) {
                    const float w = w1g[c * 25 + r * 5 + kx];   // uniform -> s_load
                    #pragma unroll
                    for (int px = 0; px < 4; ++px)
                        o[c][px] = fmaf(u[2 + px + kx], w, o[c][px]);
                }
        }
        #pragma unroll
        for (int px = 0; px < 4; ++px) {
            f16x8 hv;
            #pragma unroll
            for (int c = 0; c < 8; ++c) hv[c] = (__fp16)fmaxf(o[c][px], 0.f);
            *((f16x8*)(sh1T + ((yy + 2) * 35 + (q * 4 + px + 2)) * 8)) = hv;
        }
    }
    // B fragments: K = tap*8+ic, padded 200->208 (13 slices of 16).
    // Read straight from w2g: lane lr<16 reads ch=lr, 8 ic values per slice.
    // 12.8 KB total -> L1-hot after the first block on each CU.
    const int lr = lane & 31;          // A row (pos sub-index) / D col (channel)
    const int g2 = lane >> 5;
    int band = (lr * 57) >> 9; band = band > 2 ? 2 : band;
    const int dy = (int)((DY_TAB >> (2 * lr)) & 3ull);
    const int dx = (int)((DX_TAB >> (2 * lr)) & 3ull);
    const float biasv = (lr < 16) ? b2g[lr] : 0.f;

    f16x8 bfrag[13];
    int   toffB[13];
    #pragma unroll
    for (int s = 0; s < 13; ++s) {
        const int tap = 2 * s + g2;
        const int tapc = tap > 24 ? 24 : tap;
        f16x8 v;
        if (tap <= 24 && lr < 16) {
            const float* wp = w2g + lr * 200 + tapc;
            #pragma unroll
            for (int j = 0; j < 8; ++j) v[j] = (__fp16)wp[j * 25];
        } else {
            #pragma unroll
            for (int j = 0; j < 8; ++j) v[j] = (__fp16)0.f;
        }
        bfrag[s] = v;
        const int ky = (tapc * 13) >> 6;             // tap/5
        const int kx = tapc - 5 * ky;
        toffB[s] = (ky * 35 + kx) * 16;              // bytes
    }
    __syncthreads();   // barrier 2 (sh1T ready; spad reads done -> pooled overlay safe)

    // ---- phase C: conv2 GEMM (32x32x16) + fused relu+maxpool ----
    for (int tile = wid; tile < 27; tile += 4) {
        const int cell = tile * 3 + band;            // cells of a tile share cy
        const int cy = (cell * 57) >> 9, cx = cell - 9 * cy;
        const int R0 = 3 * cy + dy, C0 = 3 * cx + dx;
        const char* abase = (const char*)sh1T + (R0 * 35 + C0) * 16;
        f32x16 acc;
        #pragma unroll
        for (int r = 0; r < 16; ++r) acc[r] = biasv;
        #pragma unroll
        for (int s = 0; s < 13; ++s) {
            f16x8 af = *((const f16x8*)(abase + toffB[s]));
            acc = __builtin_amdgcn_mfma_f32_32x32x16_f16(af, bfrag[s], acc, 0, 0, 0);
        }
        float mA, mB, mC;   // D row = (reg&3) + 8*(reg>>2) + 4*g2
        if (g2 == 0) {
            mA = fmaxf(fmaxf(fmaxf(acc[0],acc[1]),fmaxf(acc[2],acc[3])), acc[4]);
            mB = fmaxf(fmaxf(fmaxf(acc[5],acc[6]),acc[7]), fmaxf(acc[8],acc[9]));
            mC = fmaxf(fmaxf(fmaxf(acc[10],acc[11]),acc[12]), fmaxf(acc[13],acc[14]));
        } else {
            mA = fmaxf(fmaxf(acc[0],acc[1]),fmaxf(acc[2],acc[3]));
            mB = fmaxf(fmaxf(acc[4],acc[5]),fmaxf(acc[6],acc[7]));
            mC = fmaxf(fmaxf(acc[8],acc[9]),fmaxf(acc[10],acc[11]));
        }
        mA = fmaxf(mA, 0.f); mB = fmaxf(mB, 0.f); mC = fmaxf(mC, 0.f);  // relu folded
        mA = fmaxf(mA, __shfl_xor(mA, 32, 64));
        mB = fmaxf(mB, __shfl_xor(mB, 32, 64));
        mC = fmaxf(mC, __shfl_xor(mC, 32, 64));
        if (g2 == 0 && lr < 16) {
            pooled[lr * 81 + tile * 3 + 0] = mA;
            pooled[lr * 81 + tile * 3 + 1] = mB;
            pooled[lr * 81 + tile * 3 + 2] = mC;
        }
    }
    __syncthreads();   // barrier 3

    // ---- phase D: fc partials, wave-even (81 f32x4 units per wave) ----
    {
        float part[10];
        #pragma unroll
        for (int j = 0; j < 10; ++j) part[j] = 0.f;
        const int i4e = wid * 81 + 81;
        for (int i4 = wid * 81 + lane; i4 < i4e; i4 += 64) {
            const f32x4 pv = ((const f32x4*)pooled)[i4];
            #pragma unroll
            for (int j = 0; j < 10; ++j) {
                const f32x4 fw = *((const f32x4*)(fcwg + j * 1296 + i4 * 4));
                part[j] = fmaf(pv[0], fw[0], part[j]);
                part[j] = fmaf(pv[1], fw[1], part[j]);
                part[j] = fmaf(pv[2], fw[2], part[j]);
                part[j] = fmaf(pv[3], fw[3], part[j]);
            }
        }
        #pragma unroll
        for (int j = 0; j < 10; ++j) {
            float v = part[j];
            #pragma unroll
            for (int off = 32; off > 0; off >>= 1) v += __shfl_down(v, off, 64);
            if (lane == 0) swred[wid * 10 + j] = v;
        }
    }
    __syncthreads();   // barrier 4

    // ---- phase E: softmax -> probs to global ws ----
    if (tid == 0) {
        float lg[10]; float mx = -FLT_MAX;
        #pragma unroll
        for (int j = 0; j < 10; ++j) {
            lg[j] = swred[j] + swred[10 + j] + swred[20 + j] + swred[30 + j] + fcbg[j];
            mx = fmaxf(mx, lg[j]);
        }
        float sum = 0.f; float e[10];
        #pragma unroll
        for (int j = 0; j < 10; ++j) { e[j] = expf(lg[j] - mx); sum += e[j]; }
        const float inv = 1.f / sum;
        #pragma unroll
        for (int j = 0; j < 10; ++j) wsp[(size_t)b * 16 + j] = e[j] * inv;
    }
}

// ========================= Kernel 2: scan + mix ============================
// f16 ping-pong buffers (LDS 5.1 KB), dot2 math, f32 acc. 49 threads, 1 wave.
typedef __fp16 f16x2  __attribute__((ext_vector_type(2)));
typedef unsigned int u32x2 __attribute__((ext_vector_type(2)));

__device__ inline f16x2 as_h2(unsigned u) { union { unsigned x; f16x2 h; } c; c.x = u; return c.h; }
__device__ inline unsigned pack2(float lo, float hi) {
    union { f16x2 h; unsigned x; } c; c.h[0] = (__fp16)lo; c.h[1] = (__fp16)hi; return c.x;
}
__device__ inline float dot2f(unsigned a, unsigned b, float acc) {
#if __has_builtin(__builtin_amdgcn_fdot2)
    return __builtin_amdgcn_fdot2(as_h2(a), as_h2(b), acc, false);
#else
    f16x2 ah = as_h2(a), bh = as_h2(b);
    return fmaf((float)ah[1], (float)bh[1], fmaf((float)ah[0], (float)bh[0], acc));
#endif
}
#define ALIGN16(hi, lo) __builtin_amdgcn_alignbit((hi), (lo), 16)

__global__ __launch_bounds__(64, 4) void k2_scan(
    const float* __restrict__ xg,
    const float* __restrict__ iwg,
    const float* __restrict__ wsp,
    float* __restrict__ outg)
{
    __shared__ __align__(16) char arena[5120];   // bufA f16[32][40] @0, bufB @2560
    char* bufA = arena;
    char* bufB = arena + 2560;

    const int tid = threadIdx.x;
    const int b   = blockIdx.x;

    f32x4 z4 = {0.f, 0.f, 0.f, 0.f};
    for (int i = tid; i < 320; i += 64) ((f32x4*)arena)[i] = z4;
    __syncthreads();

    for (int i = tid; i < 196; i += 64) {
        const int yy = i / 7, q = i - yy * 7;
        f32x4 v = *((const f32x4*)(xg + (size_t)b * 784 + yy * 28 + q * 4));
        unsigned* dst = (unsigned*)(bufA + (yy + 2) * 80 + q * 8 + 4);
        dst[0] = pack2(v[0], v[1]); dst[1] = pack2(v[2], v[3]);
    }
    __syncthreads();

    unsigned wp[5][3];                               // iw packed pairs (uniform)
    #pragma unroll
    for (int r = 0; r < 5; ++r) {
        wp[r][0] = pack2(iwg[r * 5 + 0], iwg[r * 5 + 1]);
        wp[r][1] = pack2(iwg[r * 5 + 2], iwg[r * 5 + 3]);
        wp[r][2] = pack2(iwg[r * 5 + 4], 0.f);
    }

    const int rq = tid / 7, qq = tid - rq * 7;       // rq 0..6 for tid<49
    const float p0 = wsp[(size_t)b * 16];
    float accv[16];
    #pragma unroll
    for (int i = 0; i < 16; ++i) accv[i] = 0.f;

    const char* cur = bufA;
    char* nxt = bufB;
    #pragma unroll 1
    for (int n = 1; n <= 9; ++n) {
        const float pn = wsp[(size_t)b * 16 + n];
        if (tid < 49) {
            float v[4][4];
            #pragma unroll
            for (int rr = 0; rr < 4; ++rr)
                #pragma unroll
                for (int px = 0; px < 4; ++px) v[rr][px] = 0.f;
            #pragma unroll
            for (int r = 0; r < 8; ++r) {
                const char* rowb = cur + (4 * rq + r) * 80 + qq * 8;
                u32x2 A = *((const u32x2*)rowb);
                u32x2 B = *((const u32x2*)(rowb + 8));
                unsigned C0 = *((const unsigned*)(rowb + 16));
                unsigned P[8] = { A.x, ALIGN16(A.y, A.x), A.y, ALIGN16(B.x, A.y),
                                  B.x, ALIGN16(B.y, B.x), B.y, ALIGN16(C0,  B.y) };
                if (n == 1 && r >= 2 && r <= 5) {    // seed: y0 = x (center cols)
                    f16x2 t1 = as_h2(A.y), t2 = as_h2(B.x);
                    accv[(r - 2) * 4 + 0] = p0 * (float)t1[0];
                    accv[(r - 2) * 4 + 1] = p0 * (float)t1[1];
                    accv[(r - 2) * 4 + 2] = p0 * (float)t2[0];
                    accv[(r - 2) * 4 + 3] = p0 * (float)t2[1];
                }
                #pragma unroll
                for (int rr = 0; rr < 4; ++rr) {
                    if (rr <= r && r <= rr + 4) {    // compile-time per (r,rr)
                        const int ky = r - rr;
                        #pragma unroll
                        for (int px = 0; px < 4; ++px) {
                            float t = v[rr][px];
                            t = dot2f(P[px],     wp[ky][0], t);
                            t = dot2f(P[px + 2], wp[ky][1], t);
                            t = dot2f(P[px + 4], wp[ky][2], t);
                            v[rr][px] = t;
                        }
                    }
                }
            }
            if (n < 9) {
                #pragma unroll
                for (int rr = 0; rr < 4; ++rr) {
                    unsigned* dst = (unsigned*)(nxt + (4 * rq + rr + 2) * 80 + qq * 8 + 4);
                    dst[0] = pack2(v[rr][0], v[rr][1]);
                    dst[1] = pack2(v[rr][2], v[rr][3]);
                }
            }
            #pragma unroll
            for (int rr = 0; rr < 4; ++rr)
                #pragma unroll
                for (int px = 0; px < 4; ++px)
                    accv[rr * 4 + px] = fmaf(pn, v[rr][px], accv[rr * 4 + px]);
        }
        if (n < 9) __syncthreads();
        const char* t = cur; cur = nxt; nxt = (char*)t;
    }

    if (tid < 49) {
        #pragma unroll
        for (int rr = 0; rr < 4; ++rr) {
            f32x4 o = {accv[rr*4], accv[rr*4+1], accv[rr*4+2], accv[rr*4+3]};
            *((f32x4*)(outg + (size_t)b * 784 + (4 * rq + rr) * 28 + qq * 4)) = o;
        }
    }
}

extern "C" void kernel_launch(void* const* d_in, const int* in_sizes, int n_in,
                              void* d_out, int out_size, void* d_ws, size_t ws_size,
                              hipStream_t stream) {
    const float* x   = (const float*)d_in[0];
    const float* w1  = (const float*)d_in[1];
    const float* b1  = (const float*)d_in[2];
    const float* w2  = (const float*)d_in[3];
    const float* b2  = (const float*)d_in[4];
    const float* fcw = (const float*)d_in[5];
    const float* fcb = (const float*)d_in[6];
    const float* iw  = (const float*)d_in[7];
    float* out = (float*)d_out;
    float* wsp = (float*)d_ws;                 // 4096*16 f32 = 256 KB of scratch
    const int B = in_sizes[0] / 784;
    k1_router<<<B, 256, 0, stream>>>(x, w1, b1, w2, b2, fcw, fcb, wsp);
    k2_scan<<<B, 64, 0, stream>>>(x, iw, wsp, out);
}

// Round 14
// 141.627 us; speedup vs baseline: 1.1570x; 1.1570x over previous
//
#include <hip/hip_runtime.h>
#include <hip/hip_bf16.h>
#include <math.h>
#include <float.h>

typedef __fp16 f16x8  __attribute__((ext_vector_type(8)));
typedef __fp16 f16x2  __attribute__((ext_vector_type(2)));
typedef float  f32x16 __attribute__((ext_vector_type(16)));
typedef float  f32x4  __attribute__((ext_vector_type(4)));
typedef unsigned int u32x2 __attribute__((ext_vector_type(2)));

__device__ inline f16x2 as_h2(unsigned u) { union { unsigned x; f16x2 h; } c; c.x = u; return c.h; }
__device__ inline unsigned pack2(float lo, float hi) {
    union { f16x2 h; unsigned x; } c; c.h[0] = (__fp16)lo; c.h[1] = (__fp16)hi; return c.x;
}
__device__ inline float dot2f(unsigned a, unsigned b, float acc) {
#if __has_builtin(__builtin_amdgcn_fdot2)
    return __builtin_amdgcn_fdot2(as_h2(a), as_h2(b), acc, false);
#else
    f16x2 ah = as_h2(a), bh = as_h2(b);
    return fmaf((float)ah[1], (float)bh[1], fmaf((float)ah[0], (float)bh[0], acc));
#endif
}
#define ALIGN16(hi, lo) __builtin_amdgcn_alignbit((hi), (lo), 16)

// Per-band sub-permutation tables (verified conflict-neutral; correctness-proven).
#define DY_TAB 0xA524A509A502A540ULL
#define DX_TAB 0x446A444A44924924ULL

// ============================ Fused kernel =============================
// conv1 -> conv2(MFMA)+pool -> fc -> softmax -> 9-step scan + mix, one block/image.
// LDS arena (28528 B, same residency as r11 k1):
//   spad   f32[32][36]   @0      4608  padded x — ALIVE whole kernel (scan seed)
//   sh1T   f16[31][35][8]@4608   17360 conv1 out; dead after GEMM ->
//     scanA f16[32][40] @4608 (2560), scanB @7168 (2560) overlay
//   sw2t   f16[25][16][8]@21968  6400  w2 [tap][ch][ic]
//     pooled f32[1296] @21968 overlay (after sw2t reads done)
//   swred  f32[40]       @28368  160   fc partials; then probs[0..9]
__global__ __launch_bounds__(256, 4) void fused(
    const float* __restrict__ xg,
    const float* __restrict__ w1g,
    const float* __restrict__ b1g,
    const float* __restrict__ w2g,
    const float* __restrict__ b2g,
    const float* __restrict__ fcwg,
    const float* __restrict__ fcbg,
    const float* __restrict__ iwg,
    float* __restrict__ outg)
{
    __shared__ __align__(16) char lds[28528];
    float*  spad   = (float*)(lds + 0);
    __fp16* sh1T   = (__fp16*)(lds + 4608);
    char*   scanA  = lds + 4608;
    char*   scanB  = lds + 7168;
    __fp16* sw2t   = (__fp16*)(lds + 21968);
    float*  pooled = (float*)(lds + 21968);
    float*  swred  = (float*)(lds + 28368);

    const int tid  = threadIdx.x;
    const int b    = blockIdx.x;
    const int lane = tid & 63;
    const int wid  = tid >> 6;

    // wave-even image task: 49 per wave (lane<49), ct in [0,196)
    const int ct = wid * 49 + lane;
    const int yy = ct / 7, q = ct - yy * 7;          // row, col-quad

    // ---- phase A: border-zero spad + border-zero sh1T + stage sw2t + load x ----
    f32x4 z4 = {0.f, 0.f, 0.f, 0.f};
    for (int i = tid; i < 92; i += 256) {            // spad border
        int row, cu;
        if (i < 36) { int r = i / 9; cu = i - 9 * r; row = r < 2 ? r : 28 + r; }
        else        { int j = i - 36; row = 2 + (j >> 1); cu = (j & 1) << 3; }
        ((f32x4*)spad)[row * 9 + cu] = z4;
    }
    for (int i = tid; i < 189; i += 256) {           // sh1T border
        int row, col;
        if (i < 105) { int r = i / 35; row = (r == 2) ? 30 : r; col = i - 35 * r; }
        else         { int j = i - 105; row = 2 + j / 3; int cm = j - 3 * (j / 3);
                       col = (cm == 2) ? 30 : cm; }
        ((f32x4*)sh1T)[row * 35 + col] = z4;
    }
    for (int i = tid; i < 400; i += 256) {           // sw2t: 1 thread = 1 (tap,ch)
        const int tap = i >> 4, ch = i & 15;
        f16x8 v;
        #pragma unroll
        for (int j = 0; j < 8; ++j) v[j] = (__fp16)w2g[ch * 200 + j * 25 + tap];
        *((f16x8*)(sw2t + i * 8)) = v;
    }
    if (lane < 49) {
        f32x4 v = *((const f32x4*)(xg + (size_t)b * 784 + yy * 28 + q * 4));
        *((f32x4*)(spad + (yy + 2) * 36 + q * 4 + 4)) = v;
    }
    __syncthreads();   // barrier 1

    // ---- phase B: conv1 f32 (49 tasks/wave) + B-fragment build from sw2t ----
    if (lane < 49) {
        float o[8][4];
        #pragma unroll
        for (int c = 0; c < 8; ++c) {
            const float bv = b1g[c];                 // uniform -> SGPR
            #pragma unroll
            for (int px = 0; px < 4; ++px) o[c][px] = bv;
        }
        #pragma unroll
        for (int r = 0; r < 5; ++r) {
            const float* rowp = spad + (yy + r) * 36 + q * 4;
            f32x4 a0 = ((const f32x4*)rowp)[0];
            f32x4 a1 = ((const f32x4*)rowp)[1];
            f32x4 a2 = ((const f32x4*)rowp)[2];
            float u[12] = {a0[0],a0[1],a0[2],a0[3], a1[0],a1[1],a1[2],a1[3],
                           a2[0],a2[1],a2[2],a2[3]};
            #pragma unroll
            for (int c = 0; c < 8; ++c)
                #pragma unroll
                for (int kx = 0; kx < 5; ++kx) {
                    const float w = w1g[c * 25 + r * 5 + kx];   // uniform -> s_load
                    #pragma unroll
                    for (int px = 0; px < 4; ++px)
                        o[c][px] = fmaf(u[2 + px + kx], w, o[c][px]);
                }
        }
        #pragma unroll
        for (int px = 0; px < 4; ++px) {
            f16x8 hv;
            #pragma unroll
            for (int c = 0; c < 8; ++c) hv[c] = (__fp16)fmaxf(o[c][px], 0.f);
            *((f16x8*)(sh1T + ((yy + 2) * 35 + (q * 4 + px + 2)) * 8)) = hv;
        }
    }
    // B fragments: K = tap*8+ic, padded 200->208 (13 slices of 16).
    const int lr = lane & 31;          // A row (pos sub-index) / D col (channel)
    const int g2 = lane >> 5;
    int band = (lr * 57) >> 9; band = band > 2 ? 2 : band;
    const int dy = (int)((DY_TAB >> (2 * lr)) & 3ull);
    const int dx = (int)((DX_TAB >> (2 * lr)) & 3ull);
    const float biasv = (lr < 16) ? b2g[lr] : 0.f;

    f16x8 bfrag[13];
    int   toffB[13];
    #pragma unroll
    for (int s = 0; s < 13; ++s) {
        const int tap = 2 * s + g2;
        const int tapc = tap > 24 ? 24 : tap;
        f16x8 v = *((const f16x8*)(sw2t + (tapc * 16 + (lr & 15)) * 8));
        if (tap > 24 || lr >= 16) {
            #pragma unroll
            for (int j = 0; j < 8; ++j) v[j] = (__fp16)0.f;
        }
        bfrag[s] = v;
        const int ky = (tapc * 13) >> 6;             // tap/5
        const int kx = tapc - 5 * ky;
        toffB[s] = (ky * 35 + kx) * 16;              // bytes
    }
    __syncthreads();   // barrier 2 (sh1T ready; sw2t reads done before pooled overlay)

    // ---- phase C: conv2 GEMM (32x32x16) + fused relu+maxpool ----
    for (int tile = wid; tile < 27; tile += 4) {
        const int cell = tile * 3 + band;
        const int cy = (cell * 57) >> 9, cx = cell - 9 * cy;
        const int R0 = 3 * cy + dy, C0 = 3 * cx + dx;
        const char* abase = (const char*)sh1T + (R0 * 35 + C0) * 16;
        f32x16 acc;
        #pragma unroll
        for (int r = 0; r < 16; ++r) acc[r] = biasv;
        #pragma unroll
        for (int s = 0; s < 13; ++s) {
            f16x8 af = *((const f16x8*)(abase + toffB[s]));
            acc = __builtin_amdgcn_mfma_f32_32x32x16_f16(af, bfrag[s], acc, 0, 0, 0);
        }
        float mA, mB, mC;   // D row = (reg&3) + 8*(reg>>2) + 4*g2
        if (g2 == 0) {
            mA = fmaxf(fmaxf(fmaxf(acc[0],acc[1]),fmaxf(acc[2],acc[3])), acc[4]);
            mB = fmaxf(fmaxf(fmaxf(acc[5],acc[6]),acc[7]), fmaxf(acc[8],acc[9]));
            mC = fmaxf(fmaxf(fmaxf(acc[10],acc[11]),acc[12]), fmaxf(acc[13],acc[14]));
        } else {
            mA = fmaxf(fmaxf(acc[0],acc[1]),fmaxf(acc[2],acc[3]));
            mB = fmaxf(fmaxf(acc[4],acc[5]),fmaxf(acc[6],acc[7]));
            mC = fmaxf(fmaxf(acc[8],acc[9]),fmaxf(acc[10],acc[11]));
        }
        mA = fmaxf(mA, 0.f); mB = fmaxf(mB, 0.f); mC = fmaxf(mC, 0.f);  // relu folded
        mA = fmaxf(mA, __shfl_xor(mA, 32, 64));
        mB = fmaxf(mB, __shfl_xor(mB, 32, 64));
        mC = fmaxf(mC, __shfl_xor(mC, 32, 64));
        if (g2 == 0 && lr < 16) {
            pooled[lr * 81 + tile * 3 + 0] = mA;
            pooled[lr * 81 + tile * 3 + 1] = mB;
            pooled[lr * 81 + tile * 3 + 2] = mC;
        }
    }
    __syncthreads();   // barrier 3 (sh1T now dead -> scanA/scanB overlay legal)

    // ---- phase D: fc partials (81 f32x4/wave) + zero scan buffers ----
    for (int i = tid; i < 320; i += 256) {           // scanA+scanB contiguous 5120 B
        ((f32x4*)scanA)[i] = z4;
        if (i + 256 < 320 || tid < 64) {}            // (no-op; loop covers 320 via 2 iters)
    }
    {
        float part[10];
        #pragma unroll
        for (int j = 0; j < 10; ++j) part[j] = 0.f;
        const int i4e = wid * 81 + 81;
        for (int i4 = wid * 81 + lane; i4 < i4e; i4 += 64) {
            const f32x4 pv = ((const f32x4*)pooled)[i4];
            #pragma unroll
            for (int j = 0; j < 10; ++j) {
                const f32x4 fw = *((const f32x4*)(fcwg + j * 1296 + i4 * 4));
                part[j] = fmaf(pv[0], fw[0], part[j]);
                part[j] = fmaf(pv[1], fw[1], part[j]);
                part[j] = fmaf(pv[2], fw[2], part[j]);
                part[j] = fmaf(pv[3], fw[3], part[j]);
            }
        }
        #pragma unroll
        for (int j = 0; j < 10; ++j) {
            float v = part[j];
            #pragma unroll
            for (int off = 32; off > 0; off >>= 1) v += __shfl_down(v, off, 64);
            if (lane == 0) swred[wid * 10 + j] = v;
        }
    }
    __syncthreads();   // barrier 4

    // ---- phase E: seed scanA interior from spad (f16) + softmax -> swred[0..9] ----
    if (lane < 49) {
        f32x4 v = *((const f32x4*)(spad + (yy + 2) * 36 + q * 4 + 4));
        unsigned* dst = (unsigned*)(scanA + (yy + 2) * 80 + q * 8 + 4);
        dst[0] = pack2(v[0], v[1]); dst[1] = pack2(v[2], v[3]);
    }
    if (tid == 0) {
        float lg[10]; float mx = -FLT_MAX;
        #pragma unroll
        for (int j = 0; j < 10; ++j) {
            lg[j] = swred[j] + swred[10 + j] + swred[20 + j] + swred[30 + j] + fcbg[j];
            mx = fmaxf(mx, lg[j]);
        }
        float sum = 0.f; float e[10];
        #pragma unroll
        for (int j = 0; j < 10; ++j) { e[j] = expf(lg[j] - mx); sum += e[j]; }
        const float inv = 1.f / sum;
        #pragma unroll
        for (int j = 0; j < 10; ++j) swred[j] = e[j] * inv;   // probs -> LDS
    }
    __syncthreads();   // barrier 5

    // ---- phase F: 9-step scan + mix (wave 0, lanes 0..48; others pass barriers) ----
    unsigned wp[5][3];                               // iw packed pairs (uniform)
    #pragma unroll
    for (int r = 0; r < 5; ++r) {
        wp[r][0] = pack2(iwg[r * 5 + 0], iwg[r * 5 + 1]);
        wp[r][1] = pack2(iwg[r * 5 + 2], iwg[r * 5 + 3]);
        wp[r][2] = pack2(iwg[r * 5 + 4], 0.f);
    }
    const int rq = tid / 7, qq = tid - rq * 7;       // valid for tid<49
    const float p0 = swred[0];
    float accv[16];
    #pragma unroll
    for (int i = 0; i < 16; ++i) accv[i] = 0.f;

    const char* cur = scanA;
    char* nxt = scanB;
    #pragma unroll 1
    for (int n = 1; n <= 9; ++n) {
        const float pn = swred[n];
        if (tid < 49) {
            float v[4][4];
            #pragma unroll
            for (int rr = 0; rr < 4; ++rr)
                #pragma unroll
                for (int px = 0; px < 4; ++px) v[rr][px] = 0.f;
            #pragma unroll
            for (int r = 0; r < 8; ++r) {
                const char* rowb = cur + (4 * rq + r) * 80 + qq * 8;
                u32x2 A = *((const u32x2*)rowb);
                u32x2 B = *((const u32x2*)(rowb + 8));
                unsigned C0 = *((const unsigned*)(rowb + 16));
                unsigned P[8] = { A.x, ALIGN16(A.y, A.x), A.y, ALIGN16(B.x, A.y),
                                  B.x, ALIGN16(B.y, B.x), B.y, ALIGN16(C0,  B.y) };
                if (n == 1 && r >= 2 && r <= 5) {    // seed: y0 = x (center cols)
                    f16x2 t1 = as_h2(A.y), t2 = as_h2(B.x);
                    accv[(r - 2) * 4 + 0] = p0 * (float)t1[0];
                    accv[(r - 2) * 4 + 1] = p0 * (float)t1[1];
                    accv[(r - 2) * 4 + 2] = p0 * (float)t2[0];
                    accv[(r - 2) * 4 + 3] = p0 * (float)t2[1];
                }
                #pragma unroll
                for (int rr = 0; rr < 4; ++rr) {
                    if (rr <= r && r <= rr + 4) {    // compile-time per (r,rr)
                        const int ky = r - rr;
                        #pragma unroll
                        for (int px = 0; px < 4; ++px) {
                            float t = v[rr][px];
                            t = dot2f(P[px],     wp[ky][0], t);
                            t = dot2f(P[px + 2], wp[ky][1], t);
                            t = dot2f(P[px + 4], wp[ky][2], t);
                            v[rr][px] = t;
                        }
                    }
                }
            }
            if (n < 9) {
                #pragma unroll
                for (int rr = 0; rr < 4; ++rr) {
                    unsigned* dst = (unsigned*)(nxt + (4 * rq + rr + 2) * 80 + qq * 8 + 4);
                    dst[0] = pack2(v[rr][0], v[rr][1]);
                    dst[1] = pack2(v[rr][2], v[rr][3]);
                }
            }
            #pragma unroll
            for (int rr = 0; rr < 4; ++rr)
                #pragma unroll
                for (int px = 0; px < 4; ++px)
                    accv[rr * 4 + px] = fmaf(pn, v[rr][px], accv[rr * 4 + px]);
        }
        if (n < 9) __syncthreads();                  // executed by ALL waves
        const char* t = cur; cur = nxt; nxt = (char*)t;
    }

    if (tid < 49) {
        #pragma unroll
        for (int rr = 0; rr < 4; ++rr) {
            f32x4 o = {accv[rr*4], accv[rr*4+1], accv[rr*4+2], accv[rr*4+3]};
            *((f32x4*)(outg + (size_t)b * 784 + (4 * rq + rr) * 28 + qq * 4)) = o;
        }
    }
}

extern "C" void kernel_launch(void* const* d_in, const int* in_sizes, int n_in,
                              void* d_out, int out_size, void* d_ws, size_t ws_size,
                              hipStream_t stream) {
    const float* x   = (const float*)d_in[0];
    const float* w1  = (const float*)d_in[1];
    const float* b1  = (const float*)d_in[2];
    const float* w2  = (const float*)d_in[3];
    const float* b2  = (const float*)d_in[4];
    const float* fcw = (const float*)d_in[5];
    const float* fcb = (const float*)d_in[6];
    const float* iw  = (const float*)d_in[7];
    float* out = (float*)d_out;
    const int B = in_sizes[0] / 784;
    fused<<<B, 256, 0, stream>>>(x, w1, b1, w2, b2, fcw, fcb, iw, out);
}

// Round 15
// 111.894 us; speedup vs baseline: 1.4645x; 1.2657x over previous
//
#include <hip/hip_runtime.h>
#include <hip/hip_bf16.h>
#include <math.h>
#include <float.h>

typedef __fp16 f16x8  __attribute__((ext_vector_type(8)));
typedef float  f32x16 __attribute__((ext_vector_type(16)));
typedef float  f32x4  __attribute__((ext_vector_type(4)));

// Per-band sub-permutation tables (verified conflict-neutral; correctness-proven).
#define DY_TAB 0xA524A509A502A540ULL
#define DX_TAB 0x446A444A44924924ULL

// ============================ Kernel 1: router =============================
// conv1(f32 fma) -> relu -> conv2(MFMA 32x32x16)+relu+maxpool -> fc -> softmax
// LDS arena (28528 B):
//   spad   f32[32][36]          @0      4608   padded input (row+2, col+4)
//   sh1T   f16[31][35][8]       @4608   17360  conv1 out, ch-innermost, stride 35
//   sw2t   f16[25][16][8]       @21968  6400   w2 as [tap][ch][ic]
//     pooled f32[1296] @21968 overlay (written after sw2t dead)
//   swred  f32[40]              @28368  160
// Best-verified structure (r11, 97.9 us). Phase A reordered: global loads
// issued before LDS zeroing so their latency hides under the stores.
__global__ __launch_bounds__(256, 4) void k1_router(
    const float* __restrict__ xg,
    const float* __restrict__ w1g,
    const float* __restrict__ b1g,
    const float* __restrict__ w2g,
    const float* __restrict__ b2g,
    const float* __restrict__ fcwg,
    const float* __restrict__ fcbg,
    float* __restrict__ wsp)
{
    __shared__ __align__(16) char lds[28528];
    float*  spad   = (float*)(lds + 0);
    __fp16* sh1T   = (__fp16*)(lds + 4608);
    __fp16* sw2t   = (__fp16*)(lds + 21968);
    float*  pooled = (float*)(lds + 21968);
    float*  swred  = (float*)(lds + 28368);

    const int tid  = threadIdx.x;
    const int b    = blockIdx.x;
    const int lane = tid & 63;
    const int wid  = tid >> 6;

    // wave-even conv1/x-load task: 49 tasks per wave (lane<49), ct in [0,196)
    const int ct = wid * 49 + lane;
    const int yy = ct / 7, q = ct - yy * 7;          // row, col-quad

    // ---- phase A: issue global loads FIRST, then LDS zeroing, then LDS writes ----
    // (1) x load (HBM/L3 latency ~500-900 cyc) — issue immediately.
    f32x4 xv = {0.f, 0.f, 0.f, 0.f};
    if (lane < 49)
        xv = *((const f32x4*)(xg + (size_t)b * 784 + yy * 28 + q * 4));
    // (2) w2 gathers for sw2t staging (L1/L2 latency) — issue next.
    //     Each of the first 400 threads handles one (tap,ch): 8 scattered 4B reads.
    float wv[8];
    const int stap = tid >> 4, sch = tid & 15;       // valid for tid<400 (all 256 are)
    {
        const float* wp = w2g + sch * 200 + stap;    // + j*25
        #pragma unroll
        for (int j = 0; j < 8; ++j) wv[j] = wp[j * 25];
    }
    // second staging task for threads 0..143 (i = tid+256)
    float wv2[8];
    const int stap2 = (tid + 256) >> 4, sch2 = (tid + 256) & 15;
    if (tid < 144) {
        const float* wp2 = w2g + sch2 * 200 + stap2;
        #pragma unroll
        for (int j = 0; j < 8; ++j) wv2[j] = wp2[j * 25];
    }
    // (3) zeroing stores run while the loads are in flight.
    f32x4 z4 = {0.f, 0.f, 0.f, 0.f};
    for (int i = tid; i < 92; i += 256) {            // spad border
        int row, cu;
        if (i < 36) { int r = i / 9; cu = i - 9 * r; row = r < 2 ? r : 28 + r; }
        else        { int j = i - 36; row = 2 + (j >> 1); cu = (j & 1) << 3; }
        ((f32x4*)spad)[row * 9 + cu] = z4;
    }
    for (int i = tid; i < 189; i += 256) {           // sh1T border
        int row, col;
        if (i < 105) { int r = i / 35; row = (r == 2) ? 30 : r; col = i - 35 * r; }
        else         { int j = i - 105; row = 2 + j / 3; int cm = j - 3 * (j / 3);
                       col = (cm == 2) ? 30 : cm; }
        ((f32x4*)sh1T)[row * 35 + col] = z4;
    }
    // (4) consume the loads: pack + LDS writes.
    {
        f16x8 v;
        #pragma unroll
        for (int j = 0; j < 8; ++j) v[j] = (__fp16)wv[j];
        *((f16x8*)(sw2t + tid * 8)) = v;
        if (tid < 144) {
            f16x8 v2;
            #pragma unroll
            for (int j = 0; j < 8; ++j) v2[j] = (__fp16)wv2[j];
            *((f16x8*)(sw2t + (tid + 256) * 8)) = v2;
        }
    }
    if (lane < 49)
        *((f32x4*)(spad + (yy + 2) * 36 + q * 4 + 4)) = xv;
    __syncthreads();   // barrier 1

    // ---- phase B: conv1 f32 (49 tasks/wave) + B-fragment build from sw2t ----
    if (lane < 49) {
        float o[8][4];
        #pragma unroll
        for (int c = 0; c < 8; ++c) {
            const float bv = b1g[c];                 // uniform -> SGPR
            #pragma unroll
            for (int px = 0; px < 4; ++px) o[c][px] = bv;
        }
        #pragma unroll
        for (int r = 0; r < 5; ++r) {
            const float* rowp = spad + (yy + r) * 36 + q * 4;
            f32x4 a0 = ((const f32x4*)rowp)[0];
            f32x4 a1 = ((const f32x4*)rowp)[1];
            f32x4 a2 = ((const f32x4*)rowp)[2];
            float u[12] = {a0[0],a0[1],a0[2],a0[3], a1[0],a1[1],a1[2],a1[3],
                           a2[0],a2[1],a2[2],a2[3]};
            #pragma unroll
            for (int c = 0; c < 8; ++c)
                #pragma unroll
                for (int kx = 0; kx < 5; ++kx) {
                    const float w = w1g[c * 25 + r * 5 + kx];   // uniform -> s_load
                    #pragma unroll
                    for (int px = 0; px < 4; ++px)
                        o[c][px] = fmaf(u[2 + px + kx], w, o[c][px]);
                }
        }
        #pragma unroll
        for (int px = 0; px < 4; ++px) {
            f16x8 hv;
            #pragma unroll
            for (int c = 0; c < 8; ++c) hv[c] = (__fp16)fmaxf(o[c][px], 0.f);
            *((f16x8*)(sh1T + ((yy + 2) * 35 + (q * 4 + px + 2)) * 8)) = hv;
        }
    }
    // B fragments: K = tap*8+ic, padded 200->208 (13 slices of 16).
    const int lr = lane & 31;          // A row (pos sub-index) / D col (channel)
    const int g2 = lane >> 5;
    int band = (lr * 57) >> 9; band = band > 2 ? 2 : band;
    const int dy = (int)((DY_TAB >> (2 * lr)) & 3ull);
    const int dx = (int)((DX_TAB >> (2 * lr)) & 3ull);
    const float biasv = (lr < 16) ? b2g[lr] : 0.f;

    f16x8 bfrag[13];
    int   toffB[13];
    #pragma unroll
    for (int s = 0; s < 13; ++s) {
        const int tap = 2 * s + g2;
        const int tapc = tap > 24 ? 24 : tap;
        f16x8 v = *((const f16x8*)(sw2t + (tapc * 16 + (lr & 15)) * 8));
        if (tap > 24 || lr >= 16) {
            #pragma unroll
            for (int j = 0; j < 8; ++j) v[j] = (__fp16)0.f;
        }
        bfrag[s] = v;
        const int ky = (tapc * 13) >> 6;             // tap/5
        const int kx = tapc - 5 * ky;
        toffB[s] = (ky * 35 + kx) * 16;              // bytes
    }
    __syncthreads();   // barrier 2 (sh1T ready; sw2t reads done before pooled overlay)

    // ---- phase C: conv2 GEMM (32x32x16) + fused relu+maxpool ----
    for (int tile = wid; tile < 27; tile += 4) {
        const int cell = tile * 3 + band;            // cells of a tile share cy
        const int cy = (cell * 57) >> 9, cx = cell - 9 * cy;
        const int R0 = 3 * cy + dy, C0 = 3 * cx + dx;
        const char* abase = (const char*)sh1T + (R0 * 35 + C0) * 16;
        f32x16 acc;
        #pragma unroll
        for (int r = 0; r < 16; ++r) acc[r] = biasv;
        #pragma unroll
        for (int s = 0; s < 13; ++s) {
            f16x8 af = *((const f16x8*)(abase + toffB[s]));
            acc = __builtin_amdgcn_mfma_f32_32x32x16_f16(af, bfrag[s], acc, 0, 0, 0);
        }
        float mA, mB, mC;   // D row = (reg&3) + 8*(reg>>2) + 4*g2
        if (g2 == 0) {
            mA = fmaxf(fmaxf(fmaxf(acc[0],acc[1]),fmaxf(acc[2],acc[3])), acc[4]);
            mB = fmaxf(fmaxf(fmaxf(acc[5],acc[6]),acc[7]), fmaxf(acc[8],acc[9]));
            mC = fmaxf(fmaxf(fmaxf(acc[10],acc[11]),acc[12]), fmaxf(acc[13],acc[14]));
        } else {
            mA = fmaxf(fmaxf(acc[0],acc[1]),fmaxf(acc[2],acc[3]));
            mB = fmaxf(fmaxf(acc[4],acc[5]),fmaxf(acc[6],acc[7]));
            mC = fmaxf(fmaxf(acc[8],acc[9]),fmaxf(acc[10],acc[11]));
        }
        mA = fmaxf(mA, 0.f); mB = fmaxf(mB, 0.f); mC = fmaxf(mC, 0.f);  // relu folded
        mA = fmaxf(mA, __shfl_xor(mA, 32, 64));
        mB = fmaxf(mB, __shfl_xor(mB, 32, 64));
        mC = fmaxf(mC, __shfl_xor(mC, 32, 64));
        if (g2 == 0 && lr < 16) {
            pooled[lr * 81 + tile * 3 + 0] = mA;
            pooled[lr * 81 + tile * 3 + 1] = mB;
            pooled[lr * 81 + tile * 3 + 2] = mC;
        }
    }
    __syncthreads();   // barrier 3

    // ---- phase D: fc partials, wave-even (81 f32x4 units per wave) ----
    {
        float part[10];
        #pragma unroll
        for (int j = 0; j < 10; ++j) part[j] = 0.f;
        const int i4e = wid * 81 + 81;
        for (int i4 = wid * 81 + lane; i4 < i4e; i4 += 64) {
            const f32x4 pv = ((const f32x4*)pooled)[i4];
            #pragma unroll
            for (int j = 0; j < 10; ++j) {
                const f32x4 fw = *((const f32x4*)(fcwg + j * 1296 + i4 * 4));
                part[j] = fmaf(pv[0], fw[0], part[j]);
                part[j] = fmaf(pv[1], fw[1], part[j]);
                part[j] = fmaf(pv[2], fw[2], part[j]);
                part[j] = fmaf(pv[3], fw[3], part[j]);
            }
        }
        #pragma unroll
        for (int j = 0; j < 10; ++j) {
            float v = part[j];
            #pragma unroll
            for (int off = 32; off > 0; off >>= 1) v += __shfl_down(v, off, 64);
            if (lane == 0) swred[wid * 10 + j] = v;
        }
    }
    __syncthreads();   // barrier 4

    // ---- phase E: softmax -> probs to global ws ----
    if (tid == 0) {
        float lg[10]; float mx = -FLT_MAX;
        #pragma unroll
        for (int j = 0; j < 10; ++j) {
            lg[j] = swred[j] + swred[10 + j] + swred[20 + j] + swred[30 + j] + fcbg[j];
            mx = fmaxf(mx, lg[j]);
        }
        float sum = 0.f; float e[10];
        #pragma unroll
        for (int j = 0; j < 10; ++j) { e[j] = expf(lg[j] - mx); sum += e[j]; }
        const float inv = 1.f / sum;
        #pragma unroll
        for (int j = 0; j < 10; ++j) wsp[(size_t)b * 16 + j] = e[j] * inv;
    }
}

// ========================= Kernel 2: scan + mix ============================
// f16 ping-pong buffers (LDS 5.1 KB), dot2 math, f32 acc. 49 threads, 1 wave.
// Probs prefetched into registers before the serial 9-step loop.
typedef __fp16 f16x2  __attribute__((ext_vector_type(2)));
typedef unsigned int u32x2 __attribute__((ext_vector_type(2)));

__device__ inline f16x2 as_h2(unsigned u) { union { unsigned x; f16x2 h; } c; c.x = u; return c.h; }
__device__ inline unsigned pack2(float lo, float hi) {
    union { f16x2 h; unsigned x; } c; c.h[0] = (__fp16)lo; c.h[1] = (__fp16)hi; return c.x;
}
__device__ inline float dot2f(unsigned a, unsigned b, float acc) {
#if __has_builtin(__builtin_amdgcn_fdot2)
    return __builtin_amdgcn_fdot2(as_h2(a), as_h2(b), acc, false);
#else
    f16x2 ah = as_h2(a), bh = as_h2(b);
    return fmaf((float)ah[1], (float)bh[1], fmaf((float)ah[0], (float)bh[0], acc));
#endif
}
#define ALIGN16(hi, lo) __builtin_amdgcn_alignbit((hi), (lo), 16)

__global__ __launch_bounds__(64, 4) void k2_scan(
    const float* __restrict__ xg,
    const float* __restrict__ iwg,
    const float* __restrict__ wsp,
    float* __restrict__ outg)
{
    __shared__ __align__(16) char arena[5120];   // bufA f16[32][40] @0, bufB @2560
    char* bufA = arena;
    char* bufB = arena + 2560;

    const int tid = threadIdx.x;
    const int b   = blockIdx.x;

    // prefetch all 10 probs (uniform s_loads) before anything serial
    float pr[10];
    #pragma unroll
    for (int j = 0; j < 10; ++j) pr[j] = wsp[(size_t)b * 16 + j];

    f32x4 z4 = {0.f, 0.f, 0.f, 0.f};
    for (int i = tid; i < 320; i += 64) ((f32x4*)arena)[i] = z4;
    __syncthreads();

    for (int i = tid; i < 196; i += 64) {
        const int yy = i / 7, q = i - yy * 7;
        f32x4 v = *((const f32x4*)(xg + (size_t)b * 784 + yy * 28 + q * 4));
        unsigned* dst = (unsigned*)(bufA + (yy + 2) * 80 + q * 8 + 4);
        dst[0] = pack2(v[0], v[1]); dst[1] = pack2(v[2], v[3]);
    }
    __syncthreads();

    unsigned wp[5][3];                               // iw packed pairs (uniform)
    #pragma unroll
    for (int r = 0; r < 5; ++r) {
        wp[r][0] = pack2(iwg[r * 5 + 0], iwg[r * 5 + 1]);
        wp[r][1] = pack2(iwg[r * 5 + 2], iwg[r * 5 + 3]);
        wp[r][2] = pack2(iwg[r * 5 + 4], 0.f);
    }

    const int rq = tid / 7, qq = tid - rq * 7;       // rq 0..6 for tid<49
    const float p0 = pr[0];
    float accv[16];
    #pragma unroll
    for (int i = 0; i < 16; ++i) accv[i] = 0.f;

    const char* cur = bufA;
    char* nxt = bufB;
    #pragma unroll 1
    for (int n = 1; n <= 9; ++n) {
        const float pn = pr[n > 9 ? 9 : n];          // register, no load in chain
        if (tid < 49) {
            float v[4][4];
            #pragma unroll
            for (int rr = 0; rr < 4; ++rr)
                #pragma unroll
                for (int px = 0; px < 4; ++px) v[rr][px] = 0.f;
            #pragma unroll
            for (int r = 0; r < 8; ++r) {
                const char* rowb = cur + (4 * rq + r) * 80 + qq * 8;
                u32x2 A = *((const u32x2*)rowb);
                u32x2 B = *((const u32x2*)(rowb + 8));
                unsigned C0 = *((const unsigned*)(rowb + 16));
                unsigned P[8] = { A.x, ALIGN16(A.y, A.x), A.y, ALIGN16(B.x, A.y),
                                  B.x, ALIGN16(B.y, B.x), B.y, ALIGN16(C0,  B.y) };
                if (n == 1 && r >= 2 && r <= 5) {    // seed: y0 = x (center cols)
                    f16x2 t1 = as_h2(A.y), t2 = as_h2(B.x);
                    accv[(r - 2) * 4 + 0] = p0 * (float)t1[0];
                    accv[(r - 2) * 4 + 1] = p0 * (float)t1[1];
                    accv[(r - 2) * 4 + 2] = p0 * (float)t2[0];
                    accv[(r - 2) * 4 + 3] = p0 * (float)t2[1];
                }
                #pragma unroll
                for (int rr = 0; rr < 4; ++rr) {
                    if (rr <= r && r <= rr + 4) {    // compile-time per (r,rr)
                        const int ky = r - rr;
                        #pragma unroll
                        for (int px = 0; px < 4; ++px) {
                            float t = v[rr][px];
                            t = dot2f(P[px],     wp[ky][0], t);
                            t = dot2f(P[px + 2], wp[ky][1], t);
                            t = dot2f(P[px + 4], wp[ky][2], t);
                            v[rr][px] = t;
                        }
                    }
                }
            }
            if (n < 9) {
                #pragma unroll
                for (int rr = 0; rr < 4; ++rr) {
                    unsigned* dst = (unsigned*)(nxt + (4 * rq + rr + 2) * 80 + qq * 8 + 4);
                    dst[0] = pack2(v[rr][0], v[rr][1]);
                    dst[1] = pack2(v[rr][2], v[rr][3]);
                }
            }
            #pragma unroll
            for (int rr = 0; rr < 4; ++rr)
                #pragma unroll
                for (int px = 0; px < 4; ++px)
                    accv[rr * 4 + px] = fmaf(pn, v[rr][px], accv[rr * 4 + px]);
        }
        if (n < 9) __syncthreads();
        const char* t = cur; cur = nxt; nxt = (char*)t;
    }

    if (tid < 49) {
        #pragma unroll
        for (int rr = 0; rr < 4; ++rr) {
            f32x4 o = {accv[rr*4], accv[rr*4+1], accv[rr*4+2], accv[rr*4+3]};
            *((f32x4*)(outg + (size_t)b * 784 + (4 * rq + rr) * 28 + qq * 4)) = o;
        }
    }
}

extern "C" void kernel_launch(void* const* d_in, const int* in_sizes, int n_in,
                              void* d_out, int out_size, void* d_ws, size_t ws_size,
                              hipStream_t stream) {
    const float* x   = (const float*)d_in[0];
    const float* w1  = (const float*)d_in[1];
    const float* b1  = (const float*)d_in[2];
    const float* w2  = (const float*)d_in[3];
    const float* b2  = (const float*)d_in[4];
    const float* fcw = (const float*)d_in[5];
    const float* fcb = (const float*)d_in[6];
    const float* iw  = (const float*)d_in[7];
    float* out = (float*)d_out;
    float* wsp = (float*)d_ws;                 // 4096*16 f32 = 256 KB of scratch
    const int B = in_sizes[0] / 784;
    k1_router<<<B, 256, 0, stream>>>(x, w1, b1, w2, b2, fcw, fcb, wsp);
    k2_scan<<<B, 64, 0, stream>>>(x, iw, wsp, out);
}